// Round 10
// baseline (472.261 us; speedup 1.0000x reference)
//
#include <hip/hip_runtime.h>
#include <hip/hip_bf16.h>
#include <hip/hip_cooperative_groups.h>

namespace cg = cooperative_groups;

#define NN 100000
#define NE 3200000
#define FIN 128
#define HD 16
#define CD 2

#define BSH 9                        // bucket shift
#define BSPAN 512                    // nodes per bucket
#define NBKT 196                     // ceil(NN / BSPAN)
#define CHUNK 8192                   // edges per partition block
#define NPB ((NE + CHUNK - 1) / CHUNK)   // 391

__device__ __forceinline__ float bf2f(ushort u) {
    union { float f; unsigned int i; } v; v.i = ((unsigned int)u) << 16; return v.f;
}
__device__ __forceinline__ ushort f2b(float f) {
    union { float f; unsigned int u; } v; v.f = f;
    unsigned int r = (v.u + 0x7FFFu + ((v.u >> 16) & 1u)) >> 16;   // RNE
    return (ushort)r;
}

// ===== cooperative mega-kernel: cnt -> colscan -> scanb -> part -> sortb -> gemm1 =====
__global__ __launch_bounds__(512) void k_mega(const int* __restrict__ src,
                                              const int* __restrict__ dst,
                                              int* __restrict__ cntmat,
                                              int* __restrict__ relm,
                                              int* __restrict__ btot,
                                              int* __restrict__ boff,
                                              unsigned int* __restrict__ csrb,
                                              int* __restrict__ csr2,
                                              int* __restrict__ rowptr,
                                              float* __restrict__ dinv,
                                              const float* __restrict__ x,
                                              const float* __restrict__ W1,
                                              ushort* __restrict__ h1b) {
    cg::grid_group grid = cg::this_grid();
    __shared__ __align__(16) char smem[8192];
    int b = blockIdx.x, t = threadIdx.x;

    // ---- phase 1: per-chunk bucket histogram -> cntmat[b][bucket] ----
    {
        int* h = (int*)smem;
        for (int i = t; i < NBKT; i += 512) h[i] = 0;
        __syncthreads();
        int cq = b * (CHUNK / 4);
        const int4* d4 = (const int4*)dst;
        #pragma unroll
        for (int j = 0; j < CHUNK / 2048; ++j) {
            int e4 = cq + j * 512 + t;
            if (e4 < NE / 4) {
                int4 d = d4[e4];
                atomicAdd(&h[d.x >> BSH], 1);
                atomicAdd(&h[d.y >> BSH], 1);
                atomicAdd(&h[d.z >> BSH], 1);
                atomicAdd(&h[d.w >> BSH], 1);
            }
        }
        __syncthreads();
        int* row = cntmat + (size_t)b * NBKT;
        for (int i = t; i < NBKT; i += 512) row[i] = h[i];
    }
    grid.sync();

    // ---- phase 2: column scan per bucket -> relm[bucket][chunk], btot ----
    if (b < NBKT) {
        int* sm = (int*)smem;
        int v = (t < NPB) ? cntmat[(size_t)t * NBKT + b] : 0;
        sm[t] = v;
        __syncthreads();
        for (int off = 1; off < 512; off <<= 1) {
            int u = 0;
            if (t >= off) u = sm[t - off];
            __syncthreads();
            if (t >= off) sm[t] += u;
            __syncthreads();
        }
        if (t < NPB) relm[(size_t)b * NPB + t] = t ? sm[t - 1] : 0;
        if (t == 511) btot[b] = sm[511];
    }
    grid.sync();

    // ---- phase 3: scan bucket totals -> boff (block 0 only) ----
    if (b == 0) {
        int* sm = (int*)smem;
        sm[t] = (t < NBKT) ? btot[t] : 0;
        __syncthreads();
        for (int off = 1; off < 512; off <<= 1) {
            int v = 0;
            if (t >= off) v = sm[t - off];
            __syncthreads();
            if (t >= off) sm[t] += v;
            __syncthreads();
        }
        if (t < NBKT) boff[t] = t ? sm[t - 1] : 0;
        if (t == 511) boff[NBKT] = sm[511];   // = NE
    }
    grid.sync();

    // ---- phase 4: deterministic partition (no global atomics) ----
    {
        int* cur = (int*)smem;
        for (int i = t; i < NBKT; i += 512)
            cur[i] = boff[i] + relm[(size_t)i * NPB + b];
        __syncthreads();
        int cq = b * (CHUNK / 4);
        const int4* s4 = (const int4*)src;
        const int4* d4 = (const int4*)dst;
        #pragma unroll
        for (int j = 0; j < CHUNK / 2048; ++j) {
            int e4 = cq + j * 512 + t;
            if (e4 < NE / 4) {
                int4 s = s4[e4];
                int4 d = d4[e4];
                int p;
                p = atomicAdd(&cur[d.x >> BSH], 1);
                csrb[p] = (unsigned)s.x | ((unsigned)(d.x & (BSPAN - 1)) << 17);
                p = atomicAdd(&cur[d.y >> BSH], 1);
                csrb[p] = (unsigned)s.y | ((unsigned)(d.y & (BSPAN - 1)) << 17);
                p = atomicAdd(&cur[d.z >> BSH], 1);
                csrb[p] = (unsigned)s.z | ((unsigned)(d.z & (BSPAN - 1)) << 17);
                p = atomicAdd(&cur[d.w >> BSH], 1);
                csrb[p] = (unsigned)s.w | ((unsigned)(d.w & (BSPAN - 1)) << 17);
            }
        }
    }
    grid.sync();

    // ---- phase 5: per-bucket counting sort -> csr2, rowptr, dinv ----
    if (b < NBKT) {
        int* scnt = (int*)smem;           // 512
        int* ssc  = scnt + BSPAN;         // 512
        int* scur = ssc + BSPAN;          // 512
        if (t < BSPAN) scnt[t] = 0;
        __syncthreads();
        int e0 = boff[b], e1 = boff[b + 1];
        for (int e = e0 + t; e < e1; e += 512) atomicAdd(&scnt[csrb[e] >> 17], 1);
        __syncthreads();
        ssc[t] = scnt[t];
        __syncthreads();
        for (int off = 1; off < BSPAN; off <<= 1) {
            int v = 0;
            if (t >= off) v = ssc[t - off];
            __syncthreads();
            if (t >= off) ssc[t] += v;
            __syncthreads();
        }
        {
            int ex = e0 + (t ? ssc[t - 1] : 0);
            scur[t] = ex;
            int node = b * BSPAN + t;
            if (node < NN) {
                rowptr[node] = ex;
                dinv[node] = rsqrtf((float)scnt[t] + 1.0f);
            }
        }
        if (b == 0 && t == 0) rowptr[NN] = boff[NBKT];   // = NE
        __syncthreads();
        for (int e = e0 + t; e < e1; e += 512) {
            unsigned p = csrb[e];
            int pos = atomicAdd(&scur[p >> 17], 1);
            csr2[pos] = (int)(p & 0x1FFFF);
        }
    }
    grid.sync();

    // ---- phase 6: h1b = bf16((x @ W1) * dinv) ; 4 threads/node, grid-stride ----
    {
        float (*wsm)[HD] = (float(*)[HD])smem;   // 8 KB
        __syncthreads();                          // smem reuse hazard
        for (int i = t; i < FIN * HD; i += 512) wsm[i >> 4][i & 15] = W1[i];
        __syncthreads();
        for (int task = b * 512 + t; task < NN * 4; task += gridDim.x * 512) {
            int node = task >> 2;
            int g = (task & 3) * 4;
            const float4* xr = (const float4*)(x + (size_t)node * FIN);
            float a0 = 0.f, a1 = 0.f, a2 = 0.f, a3 = 0.f;
            #pragma unroll
            for (int k4 = 0; k4 < FIN / 4; ++k4) {
                float4 v = xr[k4];
                #pragma unroll
                for (int kk = 0; kk < 4; ++kk) {
                    float vk = (kk == 0) ? v.x : (kk == 1) ? v.y : (kk == 2) ? v.z : v.w;
                    float4 w = *(const float4*)&wsm[k4 * 4 + kk][g];
                    a0 += vk * w.x;
                    a1 += vk * w.y;
                    a2 += vk * w.z;
                    a3 += vk * w.w;
                }
            }
            float di = dinv[node];
            ushort4 r = {f2b(a0 * di), f2b(a1 * di), f2b(a2 * di), f2b(a3 * di)};
            *(ushort4*)(h1b + (size_t)node * HD + g) = r;
        }
    }
}

// ---- layer-1 aggregate + ReLU + fused (h2 @ W2)*dinv : 4 nodes per wave ----
__global__ __launch_bounds__(256) void k_agg1(const int* __restrict__ rowptr,
                                              const int* __restrict__ csr2,
                                              const ushort* __restrict__ h1b,
                                              const float* __restrict__ dinv,
                                              const float* __restrict__ b1,
                                              const float* __restrict__ W2,
                                              float* __restrict__ g_s) {
    int wid = (blockIdx.x * 256 + threadIdx.x) >> 6;
    int lane = threadIdx.x & 63;
    int node = wid * 4 + (lane >> 4);
    if (node >= NN) return;
    int l16 = lane & 15;
    int slot = l16 >> 2;              // 0..3
    int fq = (lane & 3) * 4;          // 0,4,8,12
    int e0 = rowptr[node], e1 = rowptr[node + 1];
    float a0 = 0.f, a1 = 0.f, a2 = 0.f, a3 = 0.f;
    float c0 = 0.f, c1 = 0.f, c2 = 0.f, c3 = 0.f;
    int e = e0 + slot;
    for (; e + 4 < e1; e += 8) {                 // 2 independent chains
        int s0 = csr2[e];
        int s1 = csr2[e + 4];
        ushort4 u0 = *(const ushort4*)(h1b + (size_t)s0 * HD + fq);
        ushort4 u1 = *(const ushort4*)(h1b + (size_t)s1 * HD + fq);
        a0 += bf2f(u0.x); a1 += bf2f(u0.y); a2 += bf2f(u0.z); a3 += bf2f(u0.w);
        c0 += bf2f(u1.x); c1 += bf2f(u1.y); c2 += bf2f(u1.z); c3 += bf2f(u1.w);
    }
    if (e < e1) {
        ushort4 u = *(const ushort4*)(h1b + (size_t)csr2[e] * HD + fq);
        a0 += bf2f(u.x); a1 += bf2f(u.y); a2 += bf2f(u.z); a3 += bf2f(u.w);
    }
    a0 += c0; a1 += c1; a2 += c2; a3 += c3;
    #pragma unroll
    for (int m = 4; m <= 8; m <<= 1) {
        a0 += __shfl_xor(a0, m, 64);
        a1 += __shfl_xor(a1, m, 64);
        a2 += __shfl_xor(a2, m, 64);
        a3 += __shfl_xor(a3, m, 64);
    }
    if (slot == 0) {                  // lanes l16=0..3 hold features fq..fq+3
        float di = dinv[node];
        ushort4 us = *(const ushort4*)(h1b + (size_t)node * HD + fq);
        float v0 = fmaxf(di * (a0 + bf2f(us.x)) + b1[fq],     0.f);
        float v1 = fmaxf(di * (a1 + bf2f(us.y)) + b1[fq + 1], 0.f);
        float v2 = fmaxf(di * (a2 + bf2f(us.z)) + b1[fq + 2], 0.f);
        float v3 = fmaxf(di * (a3 + bf2f(us.w)) + b1[fq + 3], 0.f);
        float p0 = v0 * W2[fq * 2]       + v1 * W2[(fq + 1) * 2]
                 + v2 * W2[(fq + 2) * 2] + v3 * W2[(fq + 3) * 2];
        float p1 = v0 * W2[fq * 2 + 1]       + v1 * W2[(fq + 1) * 2 + 1]
                 + v2 * W2[(fq + 2) * 2 + 1] + v3 * W2[(fq + 3) * 2 + 1];
        p0 += __shfl_xor(p0, 1, 64); p0 += __shfl_xor(p0, 2, 64);
        p1 += __shfl_xor(p1, 1, 64); p1 += __shfl_xor(p1, 2, 64);
        if (l16 == 0) {
            float2 r = {p0 * di, p1 * di};
            *(float2*)(g_s + (size_t)node * 2) = r;
        }
    }
}

// ---- layer-2 aggregate: 4 nodes per wave, 8 slots x 2 feats, fused softmax ----
__global__ __launch_bounds__(256) void k_agg2(const int* __restrict__ rowptr,
                                              const int* __restrict__ csr2,
                                              const float* __restrict__ g_s,
                                              const float* __restrict__ dinv,
                                              const float* __restrict__ b2,
                                              float* __restrict__ out) {
    int wid = (blockIdx.x * 256 + threadIdx.x) >> 6;
    int lane = threadIdx.x & 63;
    int node = wid * 4 + (lane >> 4);
    if (node >= NN) return;
    int l16 = lane & 15;
    int slot = l16 >> 1, f = lane & 1;
    int e0 = rowptr[node], e1 = rowptr[node + 1];
    float acc = 0.f;
    for (int e = e0 + slot; e < e1; e += 8)
        acc += g_s[(size_t)csr2[e] * 2 + f];
    #pragma unroll
    for (int m = 2; m <= 8; m <<= 1) acc += __shfl_xor(acc, m, 64);
    if (slot == 0) {                  // lanes l16=0,1
        float di = dinv[node];
        float o = di * (acc + g_s[(size_t)node * 2 + f]) + b2[f];
        float other = __shfl_xor(o, 1, 64);
        float mx = fmaxf(o, other);
        float l = mx + logf(__expf(o - mx) + __expf(other - mx));
        out[(size_t)node * 2 + f] = o - l;
    }
}

extern "C" void kernel_launch(void* const* d_in, const int* in_sizes, int n_in,
                              void* d_out, int out_size, void* d_ws, size_t ws_size,
                              hipStream_t stream) {
    const float* x   = (const float*)d_in[0];
    const int* ei    = (const int*)d_in[1];
    const int* src   = ei;
    const int* dst   = ei + NE;
    const float* W1  = (const float*)d_in[2];
    const float* b1  = (const float*)d_in[3];
    const float* W2  = (const float*)d_in[4];
    const float* b2  = (const float*)d_in[5];
    float* out = (float*)d_out;

    char* w = (char*)d_ws;
    float* dinv        = (float*)w;          w += NN * 4;
    int*   btot        = (int*)w;            w += NBKT * 4;
    int*   boff        = (int*)w;            w += (NBKT + 1) * 4;
    int*   rowptr      = (int*)w;            w += (NN + 1) * 4;
    int*   cntmat      = (int*)w;            w += (size_t)NPB * NBKT * 4;   // 306 KB
    int*   relm        = (int*)w;            w += (size_t)NBKT * NPB * 4;   // 306 KB
    unsigned int* csrb = (unsigned int*)w;   w += (size_t)NE * 4;           // 12.8 MB
    int*   csr2        = (int*)w;            w += (size_t)NE * 4;           // 12.8 MB
    ushort* h1b        = (ushort*)w;         w += (size_t)NN * HD * 2;      // 3.2 MB
    float* g_s         = (float*)w;          w += NN * CD * 4;

    void* margs[] = { (void*)&src, (void*)&dst, (void*)&cntmat, (void*)&relm,
                      (void*)&btot, (void*)&boff, (void*)&csrb, (void*)&csr2,
                      (void*)&rowptr, (void*)&dinv, (void*)&x, (void*)&W1,
                      (void*)&h1b };
    hipLaunchCooperativeKernel((void*)k_mega, dim3(NPB), dim3(512), margs, 0, stream);
    k_agg1<<<(NN * 16 + 255) / 256, 256, 0, stream>>>(rowptr, csr2, h1b, dinv, b1, W2, g_s);
    k_agg2<<<(NN * 16 + 255) / 256, 256, 0, stream>>>(rowptr, csr2, g_s, dinv, b2, out);
}